// Round 11
// baseline (603.940 us; speedup 1.0000x reference)
//
#include <hip/hip_runtime.h>
#include <math.h>

#define NB   4096
#define LL   50
#define FF   128
#define HH   8
#define DVn  16

typedef __attribute__((ext_vector_type(8))) short bf16x8;
typedef __attribute__((ext_vector_type(4))) float f32x4;

__device__ __forceinline__ ushort bf_hi(float x) {
    uint u = __float_as_uint(x);
    uint r = u + 0x7FFFu + ((u >> 16) & 1u);   // RTNE to bf16
    return (ushort)(r >> 16);
}
__device__ __forceinline__ float bf_f(ushort b) { return __uint_as_float(((uint)b) << 16); }

// ---------------- pack: M = Wq Wk^T (A-frag), u = Wq bk, v = Wk bq, c = bq.bk, Wv ----
// v5 pack (kept): 80 blocks x 256 threads; Wq-tile + full Wk staged in LDS,
// identical e-order -> bit-identical M. Tiles 8/9 unchanged semantics.
__global__ __launch_bounds__(256)
void pack_w(const float* __restrict__ Wq, const float* __restrict__ bq,
            const float* __restrict__ Wk, const float* __restrict__ bk,
            const float* __restrict__ Wv, ushort* __restrict__ wp)
{
    __shared__ float sw[144*129];                  // 74304 B: wq 16x129, wk 128x129
    const int t    = threadIdx.x;
    const int lane = t & 63;
    const int ks   = t >> 6;
    const int h    = blockIdx.x / 10;
    const int tile = blockIdx.x % 10;
    const int c    = lane & 15;
    const int quad = lane >> 4;
    const int f0   = ks*32 + quad*8;

    float val[8];
    #pragma unroll
    for (int j = 0; j < 8; ++j) val[j] = 0.f;

    if (tile < 8) {                                // A-frag: M[16t+c][32ks+quad*8+j]
        const float* wq = Wq + (size_t)h*FF*FF;
        const float* wk = Wk + (size_t)h*FF*FF;
        float* wqs = sw;                           // 16 x 129
        float* wks = sw + 16*129;                  // 128 x 129 (all g rows)
        for (int i = t; i < 16*128; i += 256)
            wqs[(i>>7)*129 + (i&127)] = wq[(size_t)(tile*16 + (i>>7))*FF + (i&127)];
        for (int i = t; i < 128*128; i += 256)
            wks[(i>>7)*129 + (i&127)] = wk[i];
        __syncthreads();
        const int g0 = ks*32 + quad*8;
        for (int e = 0; e < FF; ++e) {             // identical order -> bit-identical M
            float qv = wqs[c*129 + e];
            #pragma unroll
            for (int j = 0; j < 8; ++j)
                val[j] += wks[(g0+j)*129 + e] * qv;
        }
    } else if (tile == 8) {                        // col0 = u = Wq bk, col1 = v = Wk bq
        const float* wq = Wq + (size_t)h*FF*FF;
        const float* wk = Wk + (size_t)h*FF*FF;
        float pu[8], pv[8];
        #pragma unroll
        for (int j = 0; j < 8; ++j) { pu[j] = 0.f; pv[j] = 0.f; }
        for (int ee = 0; ee < 8; ++ee) {           // lane c handles e in [8c, 8c+8)
            int e = c*8 + ee;
            float bkk = bk[h*FF + e], bqq = bq[h*FF + e];
            #pragma unroll
            for (int j = 0; j < 8; ++j) {
                pu[j] += wq[(size_t)(f0+j)*FF + e] * bkk;
                pv[j] += wk[(size_t)(f0+j)*FF + e] * bqq;
            }
        }
        #pragma unroll
        for (int m = 1; m < 16; m <<= 1) {         // reduce over c (quad preserved)
            #pragma unroll
            for (int j = 0; j < 8; ++j) {
                pu[j] += __shfl_xor(pu[j], m);
                pv[j] += __shfl_xor(pv[j], m);
            }
        }
        if (c == 0) {
            #pragma unroll
            for (int j = 0; j < 8; ++j) val[j] = pu[j];
        } else if (c == 1) {
            #pragma unroll
            for (int j = 0; j < 8; ++j) val[j] = pv[j];
        }
        if (ks == 0) {                             // c = bq.bk, wave-parallel
            float s = bq[h*FF + lane*2]*bk[h*FF + lane*2]
                    + bq[h*FF + lane*2 + 1]*bk[h*FF + lane*2 + 1];
            #pragma unroll
            for (int m = 1; m < 64; m <<= 1) s += __shfl_xor(s, m);
            if (lane == 0) ((float*)(wp + 327680))[h] = s;
        }
    } else {                                       // Wv B-frag
        const float* wv = Wv + (size_t)h*FF*DVn;
        #pragma unroll
        for (int j = 0; j < 8; ++j) val[j] = wv[(size_t)(f0+j)*DVn + c];
    }

    ushort hi[8], lo[8];
    #pragma unroll
    for (int j = 0; j < 8; ++j) {
        ushort hb = bf_hi(val[j]);
        hi[j] = hb;
        lo[j] = bf_hi(val[j] - bf_f(hb));
    }
    size_t base = (size_t)h*40960 + (size_t)tile*4096 + ks*1024 + lane*8;
    *(ushort4*)(wp + base)       = make_ushort4(hi[0],hi[1],hi[2],hi[3]);
    *(ushort4*)(wp + base + 4)   = make_ushort4(hi[4],hi[5],hi[6],hi[7]);
    *(ushort4*)(wp + base + 512) = make_ushort4(lo[0],lo[1],lo[2],lo[3]);
    *(ushort4*)(wp + base + 516) = make_ushort4(lo[4],lo[5],lo[6],lo[7]);
}

// ---------------- fused attention ----------------
// v12 = v11 with the REAL bug fixed: v9-v11 sized LDS at 15104 ushorts but the
//     x-hi staging + xh[16] preload span [8192, 16384) -- panels 13(part)/14/15
//     (l-tile 3, f-blocks 1-3) were read OUT OF BOUNDS -> deterministic garbage
//     in xh[13..15] -> wrong scores for m,l in [48,50) -> absmax 8.68, bit-equal
//     across all three fence variants (fences can't fix OOB). The wave-private-G
//     algebra itself audits clean (element-traced). Fix: restore v7's footprint;
//     G scratch [8192,12288) and satt [8192,13824) overlay INSIDE the dead
//     staging region [8192,16384); vf/tu/tv moved beyond it.
//     Keeps v9's structural win: barrier-free wave-private G round trip
//     (RAW fence: lgkmcnt(0)+"memory"; WAR fence: compiler barrier), 3 barriers/h
//     (24/block) vs v7's 6/h (48/block).
// LDS (ushorts; 35328 B, 3 blocks/CU):
//   xl panels [16][512] @0 (persist)
//   x-hi staging [8192,16384) (dead after reg preload)
//     == G private scratch @8192 (wave w: 8192 + w*1024; hi 512 + lo 512)
//     == satt bf16 [64][88] @8192 (overlay, barrier-separated)
//   vf @16384 (2 ks panels x 512); tu[64],tv[64] fp32 @float 8704/8768
#define XL0   0
#define XH0   8192
#define GP0   8192
#define SATT0 8192
#define SATTP 88
#define VF0   16384
#define TU0   8704
#define TV0   8768
#define LDS_FLOATS 8832

__global__ __launch_bounds__(256, 3)
void attn_fused(const float* __restrict__ hid, const ushort* __restrict__ wp,
                const float* __restrict__ ccp, const float* __restrict__ bv,
                float* __restrict__ out)
{
    __shared__ __align__(16) float lds[LDS_FLOATS];
    ushort* us = (ushort*)lds;
    float*  tu = lds + TU0;
    float*  tv = lds + TV0;

    const int t    = threadIdx.x;
    const int b    = blockIdx.x;
    const int lane = t & 63;
    const int w    = t >> 6;
    const int c16  = lane & 15;
    const int quad = lane >> 4;

    // ---- stage x -> bf16 hi/lo A-frag panels, ONCE per b (trunc split; rows >= 50
    //      garbage, masked later) ----
    {
        const float4* src = (const float4*)(hid + (size_t)b * (LL*FF));
        for (int i = t; i < 1600; i += 256) {
            float4 v = src[i];
            int l = i >> 5, f0 = (i & 31) * 4;
            int slot = ((l>>4)*4 + (f0>>5))*512 + ((l&15) + 16*((f0&31)>>3))*8 + (f0&7);
            ushort4 hv, lv;
            uint ux;
            ux = __float_as_uint(v.x); hv.x = (ushort)(ux>>16);
            lv.x = (ushort)(__float_as_uint(v.x - __uint_as_float(ux & 0xFFFF0000u))>>16);
            ux = __float_as_uint(v.y); hv.y = (ushort)(ux>>16);
            lv.y = (ushort)(__float_as_uint(v.y - __uint_as_float(ux & 0xFFFF0000u))>>16);
            ux = __float_as_uint(v.z); hv.z = (ushort)(ux>>16);
            lv.z = (ushort)(__float_as_uint(v.z - __uint_as_float(ux & 0xFFFF0000u))>>16);
            ux = __float_as_uint(v.w); hv.w = (ushort)(ux>>16);
            lv.w = (ushort)(__float_as_uint(v.w - __uint_as_float(ux & 0xFFFF0000u))>>16);
            *(ushort4*)(us + XH0 + slot) = hv;
            *(ushort4*)(us + XL0 + slot) = lv;
        }
    }
    __syncthreads();

    // ---- preload ALL 16 x-hi frags into regs; wave-own hi/lo frags into xhw/xlw ----
    bf16x8 xh[16];
    #pragma unroll
    for (int i = 0; i < 16; ++i)
        xh[i] = *(const bf16x8*)(us + XH0 + i*512 + lane*8);

    bf16x8 xlw[4];
    #pragma unroll
    for (int k = 0; k < 4; ++k)                      // runtime-w ADDRESS: rule-20 safe
        xlw[k] = *(const bf16x8*)(us + XL0 + (w*4 + k)*512 + lane*8);

    bf16x8 xhw[4];
    #pragma unroll
    for (int cw = 0; cw < 4; ++cw) if (w == cw) {    // one-time static-index copy
        #pragma unroll
        for (int k = 0; k < 4; ++k) xhw[k] = xh[cw*4 + k];
    }
    __syncthreads();                                 // xh reads done; XH -> G scratch

    const int GPw  = GP0 + w*1024;
    const int goff = (c16 + 16*(quad>>1))*8 + 4*(quad&1);   // +256 for ft-odd

    #pragma unroll 1
    for (int h = 0; h < HH; ++h) {
        const ushort* wb = wp + (size_t)h*40960 + lane*8;
        #define WFRG(tt,kk,pp) (*(const bf16x8*)(wb + (size_t)(tt)*4096 + (kk)*1024 + (pp)*512))

        f32x4 sc[4], aU, aV;
        #pragma unroll
        for (int m = 0; m < 4; ++m) sc[m] = (f32x4){0.f,0.f,0.f,0.f};
        aU = (f32x4){0.f,0.f,0.f,0.f};
        aV = (f32x4){0.f,0.f,0.f,0.f};

        // ---- barrier-free G + scores, ks-chunked; G is wave-private ----
        #pragma unroll
        for (int ks = 0; ks < 4; ++ks) {
            f32x4 aG0 = (f32x4){0.f,0.f,0.f,0.f};
            f32x4 aG1 = (f32x4){0.f,0.f,0.f,0.f};
            #pragma unroll
            for (int ksg = 0; ksg < 4; ++ksg) {      // G[f-tiles 2ks,2ks+1][m-tile w]
                bf16x8 mh0 = WFRG(2*ks,   ksg, 0), ml0 = WFRG(2*ks,   ksg, 1);
                bf16x8 mh1 = WFRG(2*ks+1, ksg, 0), ml1 = WFRG(2*ks+1, ksg, 1);
                aG0 = __builtin_amdgcn_mfma_f32_16x16x32_bf16(mh0, xhw[ksg], aG0, 0,0,0);
                aG0 = __builtin_amdgcn_mfma_f32_16x16x32_bf16(ml0, xhw[ksg], aG0, 0,0,0);
                aG0 = __builtin_amdgcn_mfma_f32_16x16x32_bf16(mh0, xlw[ksg], aG0, 0,0,0);
                aG1 = __builtin_amdgcn_mfma_f32_16x16x32_bf16(mh1, xhw[ksg], aG1, 0,0,0);
                aG1 = __builtin_amdgcn_mfma_f32_16x16x32_bf16(ml1, xhw[ksg], aG1, 0,0,0);
                aG1 = __builtin_amdgcn_mfma_f32_16x16x32_bf16(mh1, xlw[ksg], aG1, 0,0,0);
            }
            // write wave-private B-frag panel (hi @GPw, lo @GPw+512), b64s
            #pragma unroll
            for (int i = 0; i < 2; ++i) {
                const f32x4 ag = i ? aG1 : aG0;
                uint u0 = __float_as_uint(ag[0]);
                uint u1 = __float_as_uint(ag[1]);
                uint u2 = __float_as_uint(ag[2]);
                uint u3 = __float_as_uint(ag[3]);
                uint hw0 = (u0>>16) | (u1 & 0xFFFF0000u);
                uint hw1 = (u2>>16) | (u3 & 0xFFFF0000u);
                float l0 = ag[0] - __uint_as_float(u0 & 0xFFFF0000u);
                float l1 = ag[1] - __uint_as_float(u1 & 0xFFFF0000u);
                float l2 = ag[2] - __uint_as_float(u2 & 0xFFFF0000u);
                float l3 = ag[3] - __uint_as_float(u3 & 0xFFFF0000u);
                uint lw0 = (__float_as_uint(l0)>>16) | (__float_as_uint(l1) & 0xFFFF0000u);
                uint lw1 = (__float_as_uint(l2)>>16) | (__float_as_uint(l3) & 0xFFFF0000u);
                ushort* dst = us + GPw + goff + i*256;
                *(uint2*)dst         = make_uint2(hw0, hw1);
                *(uint2*)(dst + 512) = make_uint2(lw0, lw1);
            }
            // RAW fence: stores(ks) -> loads(ks). IR memory barrier + DS drain.
            asm volatile("s_waitcnt lgkmcnt(0)" ::: "memory");
            __builtin_amdgcn_sched_barrier(0);
            // read back (same wave, wave-private) and do scores for ks
            {
                bf16x8 gh = *(const bf16x8*)(us + GPw + lane*8);
                bf16x8 gl = *(const bf16x8*)(us + GPw + 512 + lane*8);
                #pragma unroll
                for (int lt = 0; lt < 4; ++lt) {
                    bf16x8 ah = xh[lt*4 + ks];               // static index
                    bf16x8 al = *(const bf16x8*)(us + XL0 + (lt*4 + ks)*512 + lane*8);
                    sc[lt] = __builtin_amdgcn_mfma_f32_16x16x32_bf16(ah, gh, sc[lt], 0,0,0);
                    sc[lt] = __builtin_amdgcn_mfma_f32_16x16x32_bf16(al, gh, sc[lt], 0,0,0);
                    sc[lt] = __builtin_amdgcn_mfma_f32_16x16x32_bf16(ah, gl, sc[lt], 0,0,0);
                }
            }
            // WAR fence: loads(ks) must stay ABOVE stores(ks+1). Zero-instruction
            // compiler barrier; same-wave DS ops execute in order at the LDS.
            asm volatile("" ::: "memory");
        }

        // ---- U/V (same ksf order as v7) ----
        #pragma unroll
        for (int ksf = 0; ksf < 4; ++ksf) {
            bf16x8 uvh = WFRG(8, ksf, 0), vvh = WFRG(9, ksf, 0);
            aU = __builtin_amdgcn_mfma_f32_16x16x32_bf16(xhw[ksf], uvh, aU, 0,0,0);
            aV = __builtin_amdgcn_mfma_f32_16x16x32_bf16(xhw[ksf], vvh, aV, 0,0,0);
            aV = __builtin_amdgcn_mfma_f32_16x16x32_bf16(xlw[ksf], vvh, aV, 0,0,0);
        }

        // ---- tu/tv/vf writes ----
        {
            if (c16 < 2) {
                float* dst = (c16 == 0) ? tu : tv;
                #pragma unroll
                for (int r = 0; r < 4; ++r) dst[w*16 + quad*4 + r] = aU[r];
            }
            float bvv = bv[h*DVn + c16];
            int ksp = w >> 1;
            #pragma unroll
            for (int r = 0; r < 4; ++r) {
                int m  = w*16 + quad*4 + r;
                int mm = (w&1)*16 + quad*4 + r;
                int Lp = c16 + 16*(mm >> 3);
                us[VF0 + ksp*512 + Lp*8 + (mm & 7)] = (m < LL) ? bf_hi(aV[r] + bvv)
                                                               : (ushort)0;
            }
        }
        __syncthreads();                            // A: tu/tv/vf visible; G reads done

        // ---- rank-1/const terms, leaky, column softmax (tu via float4) ----
        const float cc  = ccp[h];
        const int mcol  = w*16 + c16;
        const float tvv = tv[mcol] + cc;
        float mx = -INFINITY;
        #pragma unroll
        for (int mt = 0; mt < 4; ++mt) {
            const float4 tq = *(const float4*)(tu + mt*16 + quad*4);
            float tqa[4] = {tq.x, tq.y, tq.z, tq.w};
            #pragma unroll
            for (int r = 0; r < 4; ++r) {
                int l = mt*16 + quad*4 + r;
                float s = sc[mt][r] + tqa[r] + tvv;
                s = (s > 0.f) ? s : 0.1f*s;
                sc[mt][r] = s;
                if (l < LL) mx = fmaxf(mx, s);
            }
        }
        mx = fmaxf(mx, __shfl_xor(mx, 16));
        mx = fmaxf(mx, __shfl_xor(mx, 32));
        float sum = 0.f;
        #pragma unroll
        for (int mt = 0; mt < 4; ++mt)
            #pragma unroll
            for (int r = 0; r < 4; ++r) {
                int l = mt*16 + quad*4 + r;
                float p = (l < LL) ? __expf(sc[mt][r] - mx) : 0.f;
                sc[mt][r] = p;
                sum += p;
            }
        sum += __shfl_xor(sum, 16);
        sum += __shfl_xor(sum, 32);
        float inv = 1.0f / sum;

        // satt bf16 [64][88] overlaid on G scratch; cols >=50 zeroed
        #pragma unroll
        for (int mt = 0; mt < 4; ++mt)
            #pragma unroll
            for (int r = 0; r < 4; ++r) {
                int l = mt*16 + quad*4 + r;
                us[SATT0 + l*SATTP + mcol] = (mcol < LL) ? bf_hi(sc[mt][r] * inv) : (ushort)0;
            }
        __syncthreads();                            // B: satt visible

        // ---- out = relu(att.V) via MFMA; wave w owns l-tile w ----
        f32x4 ao = (f32x4){0.f,0.f,0.f,0.f};
        #pragma unroll
        for (int ksp = 0; ksp < 2; ++ksp) {
            bf16x8 af = *(const bf16x8*)(us + SATT0 + (w*16 + c16)*SATTP + ksp*32 + quad*8);
            bf16x8 bf = *(const bf16x8*)(us + VF0 + ksp*512 + lane*8);
            ao = __builtin_amdgcn_mfma_f32_16x16x32_bf16(af, bf, ao, 0,0,0);
        }
        #pragma unroll
        for (int r = 0; r < 4; ++r) {
            int l = w*16 + quad*4 + r;
            if (l < LL)
                out[(size_t)b*(LL*FF) + l*FF + h*DVn + c16] = fmaxf(ao[r], 0.f);
        }
        __syncthreads();                            // C: protect satt/vf/tu/tv for next h
    }
}

extern "C" void kernel_launch(void* const* d_in, const int* in_sizes, int n_in,
                              void* d_out, int out_size, void* d_ws, size_t ws_size,
                              hipStream_t stream)
{
    const float* hid = (const float*)d_in[0];
    const float* Wq  = (const float*)d_in[1];
    const float* bq  = (const float*)d_in[2];
    const float* Wk  = (const float*)d_in[3];
    const float* bk  = (const float*)d_in[4];
    const float* Wv  = (const float*)d_in[5];
    const float* bv  = (const float*)d_in[6];
    float* o    = (float*)d_out;
    ushort* wp  = (ushort*)d_ws;                       // 655392 B used
    const float* ccp = (const float*)(wp + 327680);

    pack_w<<<dim3(80), dim3(256), 0, stream>>>(Wq, bq, Wk, bk, Wv, wp);
    attn_fused<<<dim3(NB), dim3(256), 0, stream>>>(hid, wp, ccp, bv, o);
}